// Round 6
// baseline (133.356 us; speedup 1.0000x reference)
//
#include <hip/hip_runtime.h>
#include <stdint.h>

#define RES 64
#define NVOX (RES * RES * RES)
#define NPTS 4194304
#define TPB 512
#define MAIN_BLOCKS (NPTS / 8 / TPB)   // 1024 blocks, 8 pts/thread

// Workspace layout:
//   [0, NVOX*4)               : quantized table, 1 uint32/voxel (10/10/10 xyz)
//   [NVOX*4, NVOX*4 + NVOX/8) : voxel mask bitfield (32 KB)

__global__ __launch_bounds__(256) void build_table_kernel(
    const float* __restrict__ cp, const int* __restrict__ vox,
    uint32_t* __restrict__ tq, unsigned long long* __restrict__ mbits)
{
    int i = blockIdx.x * 256 + threadIdx.x;   // grid exactly covers NVOX
    float x = cp[3 * i + 0];
    float y = cp[3 * i + 1];
    float z = cp[3 * i + 2];
    uint32_t qx = (uint32_t)__float2int_rn(fminf(fmaxf(x, 0.f), 1.f) * 1023.0f);
    uint32_t qy = (uint32_t)__float2int_rn(fminf(fmaxf(y, 0.f), 1.f) * 1023.0f);
    uint32_t qz = (uint32_t)__float2int_rn(fminf(fmaxf(z, 0.f), 1.f) * 1023.0f);
    tq[i] = qx | (qy << 10) | (qz << 20);

    unsigned long long b = __ballot(vox[i] != 0);
    if ((threadIdx.x & 63) == 0) mbits[i >> 6] = b;
}

__global__ __launch_bounds__(TPB) void sym_loss_kernel(
    const float4* __restrict__ pts,     // N*3 floats viewed as float4
    const float* __restrict__ planes,   // 3x4
    const float* __restrict__ axes,     // 3x4
    const uint32_t* __restrict__ tq,    // NVOX quantized entries
    const uint32_t* __restrict__ mbits, // NVOX bits (8192 dwords)
    float* __restrict__ out)
{
    __shared__ uint32_t smask[NVOX / 32];   // 32 KB
    __shared__ float sacc[TPB / 64];

    const int tid = threadIdx.x;
#pragma unroll
    for (int i = 0; i < NVOX / 32 / TPB; ++i)
        smask[i * TPB + tid] = mbits[i * TPB + tid];

    // ---- Uniform per-transform constants (wave-uniform -> SGPRs) ----
    // All transforms emit coordinates in "scaled space" s = 64 * t.
    // Reflections: coef = p.n + d ; s_i = 64*p_i + coef * (-64*f*n_i)
    float rnx[3], rny[3], rnz[3], rdd[3], nnx[3], nny[3], nnz[3];
#pragma unroll
    for (int k = 0; k < 3; ++k) {
        float a = planes[4 * k + 0], b = planes[4 * k + 1];
        float c = planes[4 * k + 2], d = planes[4 * k + 3];
        float f = 2.0f / (a * a + b * b + c * c);
        rnx[k] = a; rny[k] = b; rnz[k] = c; rdd[k] = d;
        nnx[k] = -64.0f * f * a;
        nny[k] = -64.0f * f * b;
        nnz[k] = -64.0f * f * c;
    }
    // Rotations as 3x3 matrices (x64): M = 64*[(w^2-|v|^2)I + 2vv^T + 2w[v]x]
    float M0[9], M1[9], M2[9];
    {
#pragma unroll
        for (int k = 0; k < 3; ++k) {
            float w = axes[4 * k + 0], x = axes[4 * k + 1];
            float y = axes[4 * k + 2], z = axes[4 * k + 3];
            float qs = w * w - (x * x + y * y + z * z);
            float* M = (k == 0) ? M0 : (k == 1) ? M1 : M2;
            M[0] = 64.0f * (qs + 2.0f * x * x);
            M[1] = 128.0f * (x * y - w * z);
            M[2] = 128.0f * (x * z + w * y);
            M[3] = 128.0f * (x * y + w * z);
            M[4] = 64.0f * (qs + 2.0f * y * y);
            M[5] = 128.0f * (y * z - w * x);
            M[6] = 128.0f * (x * z - w * y);
            M[7] = 128.0f * (y * z + w * x);
            M[8] = 64.0f * (qs + 2.0f * z * z);
        }
    }

    __syncthreads();

    const int gid    = blockIdx.x * TPB + tid;
    const int stride = MAIN_BLOCKS * TPB;     // total threads; 2 quad-groups each
    const float K = 64.0f / 1023.0f;          // dequant into scaled space

    float acc = 0.0f;
#pragma unroll
    for (int g = 0; g < 2; ++g) {
        int base = gid + g * stride;          // quad-group index
        float4 f0 = pts[3 * base + 0];
        float4 f1 = pts[3 * base + 1];
        float4 f2 = pts[3 * base + 2];
        float px[4] = {f0.x, f0.w, f1.z, f2.y};
        float py[4] = {f0.y, f1.x, f1.w, f2.z};
        float pz[4] = {f0.z, f1.y, f2.x, f2.w};

#pragma unroll
        for (int j = 0; j < 4; ++j) {
            float x = px[j], y = py[j], z = pz[j];
            float p64x = 64.0f * x, p64y = 64.0f * y, p64z = 64.0f * z;
            float sx[6], sy[6], sz[6];

            // 3 reflections: 6 fma each
#pragma unroll
            for (int k = 0; k < 3; ++k) {
                float coef = fmaf(x, rnx[k], fmaf(y, rny[k], fmaf(z, rnz[k], rdd[k])));
                sx[k] = fmaf(coef, nnx[k], p64x);
                sy[k] = fmaf(coef, nny[k], p64y);
                sz[k] = fmaf(coef, nnz[k], p64z);
            }
            // 3 rotations: 9 fma each (matrix rows)
            sx[3] = fmaf(M0[0], x, fmaf(M0[1], y, M0[2] * z));
            sy[3] = fmaf(M0[3], x, fmaf(M0[4], y, M0[5] * z));
            sz[3] = fmaf(M0[6], x, fmaf(M0[7], y, M0[8] * z));
            sx[4] = fmaf(M1[0], x, fmaf(M1[1], y, M1[2] * z));
            sy[4] = fmaf(M1[3], x, fmaf(M1[4], y, M1[5] * z));
            sz[4] = fmaf(M1[6], x, fmaf(M1[7], y, M1[8] * z));
            sx[5] = fmaf(M2[0], x, fmaf(M2[1], y, M2[2] * z));
            sy[5] = fmaf(M2[3], x, fmaf(M2[4], y, M2[5] * z));
            sz[5] = fmaf(M2[6], x, fmaf(M2[7], y, M2[8] * z));

            // Index + LDS mask gate + batched gathers.
            uint32_t e[6];
            float    mm[6];
#pragma unroll
            for (int t = 0; t < 6; ++t) {
                // trunc == floor after clamping to [0,63]; no floorf needed
                int ix = (int)__builtin_amdgcn_fmed3f(sx[t], 0.0f, 63.0f);
                int iy = (int)__builtin_amdgcn_fmed3f(sy[t], 0.0f, 63.0f);
                int iz = (int)__builtin_amdgcn_fmed3f(sz[t], 0.0f, 63.0f);
                uint32_t idx = (uint32_t)((ix << 12) | (iy << 6) | iz);
                uint32_t bit = (smask[idx >> 5] >> (idx & 31)) & 1u;
                mm[t] = (float)bit;
                e[t]  = tq[bit ? idx : 0u];
            }

#pragma unroll
            for (int t = 0; t < 6; ++t) {
                uint32_t w = e[t];
                float dx = sx[t] - (float)(w & 1023u)         * K;
                float dy = sy[t] - (float)((w >> 10) & 1023u) * K;
                float dz = sz[t] - (float)((w >> 20) & 1023u) * K;
                float d2 = fmaf(dx, dx, fmaf(dy, dy, dz * dz));
                acc = fmaf(__builtin_amdgcn_sqrtf(d2), mm[t], acc);
            }
        }
    }

    // Reduce: wave64 shfl -> LDS -> one atomic per block.
#pragma unroll
    for (int off = 32; off > 0; off >>= 1)
        acc += __shfl_down(acc, off, 64);

    int lane = tid & 63;
    int wid  = tid >> 6;
    if (lane == 0) sacc[wid] = acc;
    __syncthreads();
    if (tid == 0) {
        float s = 0.0f;
#pragma unroll
        for (int wv = 0; wv < TPB / 64; ++wv) s += sacc[wv];
        atomicAdd(out, s * (1.0f / ((float)NPTS * 64.0f)));
    }
}

extern "C" void kernel_launch(void* const* d_in, const int* in_sizes, int n_in,
                              void* d_out, int out_size, void* d_ws, size_t ws_size,
                              hipStream_t stream)
{
    const float* sample_points = (const float*)d_in[0];
    const float* closest       = (const float*)d_in[1];
    const int*   voxels        = (const int*)d_in[2];
    const float* planes        = (const float*)d_in[3];
    const float* axes          = (const float*)d_in[4];
    float*       out           = (float*)d_out;

    uint32_t*           tq    = (uint32_t*)d_ws;                                // 1 MB
    unsigned long long* mbits = (unsigned long long*)((char*)d_ws + NVOX * 4);  // 32 KB

    (void)hipMemsetAsync(out, 0, sizeof(float), stream);
    build_table_kernel<<<NVOX / 256, 256, 0, stream>>>(closest, voxels, tq, mbits);
    sym_loss_kernel<<<MAIN_BLOCKS, TPB, 0, stream>>>(
        (const float4*)sample_points, planes, axes, tq,
        (const uint32_t*)mbits, out);
}